// Round 9
// baseline (1181.159 us; speedup 1.0000x reference)
//
#include <hip/hip_runtime.h>
#include <hip/hip_bf16.h>

#define NN 100000
#define NE 1600000
// D_H = D_E = D_Q = 64, D_HID = 128, N_GRAPHS = 16

typedef __attribute__((ext_vector_type(8))) unsigned short ushort8v;
typedef __attribute__((ext_vector_type(8))) short short8v;
typedef __attribute__((ext_vector_type(4))) float f32x4;

__device__ __forceinline__ float b2f(unsigned short u) {
  return __uint_as_float(((unsigned)u) << 16);
}
// f32 -> bf16 bits, round-to-nearest-even
__device__ __forceinline__ short f2bs(float f) {
  unsigned u = __float_as_uint(f);
  unsigned r = (u + 0x7FFFu + ((u >> 16) & 1u)) >> 16;
  return (short)r;
}

// Qg[g][j] = gate_b1[j] + sum_k q[g][k] * gate_w1[128+k][j]
__global__ void qproj_kernel(const float* __restrict__ q,
                             const float* __restrict__ gw1,
                             const float* __restrict__ gb1,
                             float* __restrict__ Qg) {
  int g = blockIdx.x, j = threadIdx.x;
  float acc = gb1[j];
  for (int k = 0; k < 64; ++k) acc += q[g * 64 + k] * gw1[(128 + k) * 128 + j];
  Qg[g * 128 + j] = acc;
}

// Prepack score_w1 e-part into bf16 MFMA A-fragments with REMAPPED rows:
// tile (t,ks), lane (qg,cl), elem j -> A row cl = hidden dim
// d = 32*(cl>>2) + 4*t + (cl&3), k = ks*32 + qg*8 + j.
// After MFMA, lane (qg,cl) owns C rows qg*4+i = dims 32qg+4t+i (contiguous
// 32-dim block per qg across the t loop).
__global__ __launch_bounds__(1024) void prepack_kernel(
    const float* __restrict__ sw1, short8v* __restrict__ WtG) {
  int tid = threadIdx.x;
  int t = tid >> 7, ks = (tid >> 6) & 1, lane = tid & 63;
  int qg = lane >> 4, cl = lane & 15;
  int d = 32 * (cl >> 2) + 4 * t + (cl & 3);
  short8v fr;
#pragma unroll
  for (int j = 0; j < 8; ++j)
    fr[j] = f2bs(sw1[(128 + ks * 32 + qg * 8 + j) * 128 + d]);
  WtG[tid] = fr;
}

// Node projections -> interleaved bf16 rows [N][256]:
// SRCP[n] = [GA(32qg..)|SA(32qg..)] x4 qg-chunks; DSTP[n] = [GB|SB] same.
// part 0: GA->SRCP+0  part 1: SA->SRCP+32  part 2: GB->DSTP+0  part 3: SB->DSTP+32
__global__ __launch_bounds__(256) void nodeproj_kernel(
    const float* __restrict__ h, const float* __restrict__ gw1,
    const float* __restrict__ sw1, __hip_bfloat16* __restrict__ SRCP,
    __hip_bfloat16* __restrict__ DSTP) {
  __shared__ float hs[64][64];   // [k][n]
  __shared__ float Ws[64][128];  // [k][c]
  int part = blockIdx.y;
  const float* W = (part & 1) ? sw1 : gw1;
  int roff = (part >= 2) ? 64 : 0;
  __hip_bfloat16* outp = (part >= 2) ? DSTP : SRCP;
  int goff = (part & 1) ? 32 : 0;
  int n0 = blockIdx.x * 64;
  int t = threadIdx.x;

  {
    int n = t & 63, kc = t >> 6;
    int gn = n0 + n;
#pragma unroll
    for (int i = 0; i < 4; ++i) {
      int k = kc * 16 + i * 4;
      float4 hv = make_float4(0.f, 0.f, 0.f, 0.f);
      if (gn < NN) hv = *(const float4*)&h[gn * 64 + k];
      hs[k + 0][n] = hv.x; hs[k + 1][n] = hv.y;
      hs[k + 2][n] = hv.z; hs[k + 3][n] = hv.w;
    }
  }
  {
    const float* Wb = W + roff * 128;
    float* wsf = &Ws[0][0];
#pragma unroll
    for (int i = 0; i < 8; ++i) {
      int flat = (i * 256 + t) * 4;
      *(float4*)&wsf[flat] = *(const float4*)&Wb[flat];
    }
  }
  __syncthreads();

  int tx = t & 31, ty = t >> 5;
  float acc[8][4] = {};
#pragma unroll 4
  for (int k = 0; k < 64; ++k) {
    float hn[8];
    *(float4*)&hn[0] = *(const float4*)&hs[k][ty * 8];
    *(float4*)&hn[4] = *(const float4*)&hs[k][ty * 8 + 4];
    float wv[4];
#pragma unroll
    for (int i = 0; i < 4; ++i) wv[i] = Ws[k][tx + 32 * i];
#pragma unroll
    for (int j = 0; j < 8; ++j)
#pragma unroll
      for (int i = 0; i < 4; ++i) acc[j][i] += hn[j] * wv[i];
  }
#pragma unroll
  for (int j = 0; j < 8; ++j) {
    int gn = n0 + ty * 8 + j;
    if (gn < NN) {
      // col c = tx+32i -> row offset (c>>5)*64 + goff + (c&31) = i*64+goff+tx
#pragma unroll
      for (int i = 0; i < 4; ++i)
        outp[(size_t)gn * 256 + i * 64 + goff + tx] = __float2bfloat16(acc[j][i]);
    }
  }
}

// Fused edge kernel v3: per rt, each lane gathers ONE 128B contiguous block
// per src + per dst (8+8 x16B from 2 bases) + 4 e-loads. Score dims remapped
// to 32qg+4t+i (contiguous per qg). QgS padded stride 33.
__global__ __launch_bounds__(256, 4) void edge_kernel(
    const float* __restrict__ e, const int* __restrict__ eidx,
    const int* __restrict__ ebat,
    const __hip_bfloat16* __restrict__ SRCP, const __hip_bfloat16* __restrict__ DSTP,
    const float* __restrict__ Qg, const short8v* __restrict__ WtG,
    const float* __restrict__ sb1, const float* __restrict__ gw2,
    const float* __restrict__ gb2, const float* __restrict__ sw2,
    const float* __restrict__ sb2, float* __restrict__ out,
    float* __restrict__ nsum) {
  __shared__ short8v WtS[1024];    // 16 KB W fragments
  __shared__ f32x4 QgS[16 * 33];   // 8.4 KB padded
  __shared__ f32x4 gw2S[32], sb1S[32], sw2S[32];  // 1.5 KB
  const int tid = threadIdx.x;
  const int w = tid >> 6, lane = tid & 63;
  const int qg = lane >> 4, cl = lane & 15;
  const int EB = blockIdx.x * 256 + w * 64;
  const unsigned short* SU = (const unsigned short*)SRCP;
  const unsigned short* DU = (const unsigned short*)DSTP;
  const float sb2v = sb2[0], gb2v = gb2[0];

  // prefetch rt=0 indices (overlaps LDS staging)
  int srcv = eidx[EB + cl];
  int dstv = eidx[NE + EB + cl];
  int gv   = ebat[EB + cl];

  {  // stage LDS
    const f32x4* s4 = (const f32x4*)WtG;
    f32x4* d4 = (f32x4*)WtS;
#pragma unroll
    for (int i = 0; i < 4; ++i) d4[tid + i * 256] = s4[tid + i * 256];
    const f32x4* q4 = (const f32x4*)Qg;
    QgS[(tid >> 5) * 33 + (tid & 31)] = q4[tid];
    {
      int t2 = tid + 256;
      QgS[(t2 >> 5) * 33 + (t2 & 31)] = q4[t2];
    }
    if (tid < 32) {
      gw2S[tid] = ((const f32x4*)gw2)[tid];
      sb1S[tid] = ((const f32x4*)sb1)[tid];
      sw2S[tid] = ((const f32x4*)sw2)[tid];
    }
  }
  __syncthreads();

#pragma unroll 1
  for (int rt = 0; rt < 4; ++rt) {
    const int erow = EB + rt * 16 + cl;  // this lane's edge

    // ---- issue ALL loads for this rt upfront ----
    const float* ap = e + (size_t)erow * 64 + qg * 8;
    f32x4 f0 = __builtin_nontemporal_load((const f32x4*)(ap + 0));
    f32x4 f1 = __builtin_nontemporal_load((const f32x4*)(ap + 4));
    f32x4 f2 = __builtin_nontemporal_load((const f32x4*)(ap + 32));
    f32x4 f3 = __builtin_nontemporal_load((const f32x4*)(ap + 36));

    // src row: 128B contiguous = [gate 64B | score 64B] for this qg
    const ushort8v* sp = (const ushort8v*)(SU + (size_t)srcv * 256 + qg * 64);
    const ushort8v* dp = (const ushort8v*)(DU + (size_t)dstv * 256 + qg * 64);
    ushort8v gav[4], gbv[4], sav[4], sbv[4];
#pragma unroll
    for (int c = 0; c < 4; ++c) {
      gav[c] = sp[c];
      gbv[c] = dp[c];
      sav[c] = sp[4 + c];
      sbv[c] = dp[4 + c];
    }

    // prefetch next rt's indices (named scalars)
    int srcn = srcv, dstn = dstv, gn = gv;
    if (rt < 3) {
      int er2 = erow + 16;
      srcn = eidx[er2];
      dstn = eidx[NE + er2];
      gn   = ebat[er2];
    }

    // e -> bf16 fragments while gathers are in flight
    short8v b0, b1;
    b0[0] = f2bs(f0.x); b0[1] = f2bs(f0.y); b0[2] = f2bs(f0.z); b0[3] = f2bs(f0.w);
    b0[4] = f2bs(f1.x); b0[5] = f2bs(f1.y); b0[6] = f2bs(f1.z); b0[7] = f2bs(f1.w);
    b1[0] = f2bs(f2.x); b1[1] = f2bs(f2.y); b1[2] = f2bs(f2.z); b1[3] = f2bs(f2.w);
    b1[4] = f2bs(f3.x); b1[5] = f2bs(f3.y); b1[6] = f2bs(f3.z); b1[7] = f2bs(f3.w);

    // ---- gate compute: dims 32qg+8c+k ----
    float gpart = 0.f;
#pragma unroll
    for (int c = 0; c < 4; ++c) {
      ushort8v av = gav[c], bv = gbv[c];
      f32x4 q0 = QgS[gv * 33 + qg * 8 + c * 2];
      f32x4 q1 = QgS[gv * 33 + qg * 8 + c * 2 + 1];
      f32x4 w0 = gw2S[qg * 8 + c * 2];
      f32x4 w1 = gw2S[qg * 8 + c * 2 + 1];
#pragma unroll
      for (int ii = 0; ii < 4; ++ii) {
        float x = b2f(av[ii]) + b2f(bv[ii]) + q0[ii];
        gpart = fmaf(fmaxf(x, 0.f), w0[ii], gpart);
      }
#pragma unroll
      for (int ii = 0; ii < 4; ++ii) {
        float x = b2f(av[4 + ii]) + b2f(bv[4 + ii]) + q1[ii];
        gpart = fmaf(fmaxf(x, 0.f), w1[ii], gpart);
      }
    }

    // ---- score compute: MFMA + epilogue (lane dims 32qg+4t+i) ----
    float part = 0.f;
#pragma unroll
    for (int t = 0; t < 8; ++t) {
      short8v Aw0 = WtS[(t * 2 + 0) * 64 + lane];
      short8v Aw1 = WtS[(t * 2 + 1) * 64 + lane];
      f32x4 acc = (f32x4){0.f, 0.f, 0.f, 0.f};
      acc = __builtin_amdgcn_mfma_f32_16x16x32_bf16(Aw0, b0, acc, 0, 0, 0);
      acc = __builtin_amdgcn_mfma_f32_16x16x32_bf16(Aw1, b1, acc, 0, 0, 0);
      f32x4 bb = sb1S[qg * 8 + t];
      f32x4 ww = sw2S[qg * 8 + t];
#pragma unroll
      for (int i = 0; i < 4; ++i) {
        float sx = acc[i] + b2f(sav[t >> 1][(t & 1) * 4 + i]) +
                   b2f(sbv[t >> 1][(t & 1) * 4 + i]) + bb[i];
        part = fmaf(fmaxf(sx, 0.f), ww[i], part);
      }
    }

    // ---- reduce over qg groups; finalize ----
    part += __shfl_xor(part, 16, 64);
    part += __shfl_xor(part, 32, 64);
    gpart += __shfl_xor(gpart, 16, 64);
    gpart += __shfl_xor(gpart, 32, 64);
    if (lane < 16) {
      int E = EB + rt * 16 + cl;
      float gate = 1.f / (1.f + __expf(-(gpart + gb2v)));
      float ex = __expf(gate * (part + sb2v));
      out[E] = ex;
      atomicAdd(&nsum[dstv], ex);
    }
    srcv = srcn; dstv = dstn; gv = gn;
  }
}

__global__ __launch_bounds__(256) void norm_kernel(
    const int* __restrict__ eidx, const float* __restrict__ nodesum,
    float* __restrict__ out) {
  int ee = blockIdx.x * 256 + threadIdx.x;
  int dst = eidx[NE + ee];
  out[ee] = out[ee] / fmaxf(nodesum[dst], 1e-9f);
}

extern "C" void kernel_launch(void* const* d_in, const int* in_sizes, int n_in,
                              void* d_out, int out_size, void* d_ws, size_t ws_size,
                              hipStream_t stream) {
  const float* h   = (const float*)d_in[0];
  const float* e   = (const float*)d_in[1];
  const float* q   = (const float*)d_in[2];
  const int* eidx  = (const int*)d_in[3];
  const int* ebat  = (const int*)d_in[4];
  const float* gw1 = (const float*)d_in[5];
  const float* gb1 = (const float*)d_in[6];
  const float* gw2 = (const float*)d_in[7];
  const float* gb2 = (const float*)d_in[8];
  const float* sw1 = (const float*)d_in[9];
  const float* sb1 = (const float*)d_in[10];
  const float* sw2 = (const float*)d_in[11];
  const float* sb2 = (const float*)d_in[12];
  float* out = (float*)d_out;

  char* ws = (char*)d_ws;
  // SRCP 51.2MB | DSTP 51.2MB | Qg 8KB | WtG 16KB | nsum 400KB
  __hip_bfloat16* SRCP = (__hip_bfloat16*)ws;
  __hip_bfloat16* DSTP = (__hip_bfloat16*)(ws + 51200000);
  float* Qg    = (float*)(ws + 102400000);
  short8v* WtG = (short8v*)(ws + 102400000 + 8192);
  float* nsum  = (float*)(ws + 102400000 + 8192 + 16384);

  (void)hipMemsetAsync(nsum, 0, 400000, stream);
  qproj_kernel<<<dim3(16), dim3(128), 0, stream>>>(q, gw1, gb1, Qg);
  prepack_kernel<<<dim3(1), dim3(1024), 0, stream>>>(sw1, WtG);
  nodeproj_kernel<<<dim3(1563, 4), dim3(256), 0, stream>>>(h, gw1, sw1, SRCP, DSTP);
  edge_kernel<<<dim3(NE / 256), dim3(256), 0, stream>>>(
      e, eidx, ebat, SRCP, DSTP, Qg, WtG, sb1, gw2, gb2, sw2, sb2, out, nsum);
  norm_kernel<<<dim3(NE / 256), dim3(256), 0, stream>>>(eidx, nsum, out);
}

// Round 10
// 547.413 us; speedup vs baseline: 2.1577x; 2.1577x over previous
//
#include <hip/hip_runtime.h>
#include <hip/hip_bf16.h>

#define NN 100000
#define NE 1600000
// D_H = D_E = D_Q = 64, D_HID = 128, N_GRAPHS = 16

typedef __attribute__((ext_vector_type(8))) unsigned short ushort8v;
typedef __attribute__((ext_vector_type(8))) short short8v;
typedef __attribute__((ext_vector_type(4))) float f32x4;

__device__ __forceinline__ float b2f(unsigned short u) {
  return __uint_as_float(((unsigned)u) << 16);
}
// f32 -> bf16 bits, round-to-nearest-even
__device__ __forceinline__ short f2bs(float f) {
  unsigned u = __float_as_uint(f);
  unsigned r = (u + 0x7FFFu + ((u >> 16) & 1u)) >> 16;
  return (short)r;
}

// Qg[g][j] = gate_b1[j] + sum_k q[g][k] * gate_w1[128+k][j]
__global__ void qproj_kernel(const float* __restrict__ q,
                             const float* __restrict__ gw1,
                             const float* __restrict__ gb1,
                             float* __restrict__ Qg) {
  int g = blockIdx.x, j = threadIdx.x;
  float acc = gb1[j];
  for (int k = 0; k < 64; ++k) acc += q[g * 64 + k] * gw1[(128 + k) * 128 + j];
  Qg[g * 128 + j] = acc;
}

// Prepack score_w1 e-part into bf16 MFMA A-fragments with REMAPPED rows:
// tile (t,ks), lane (qg,cl), elem j -> A row cl = hidden dim
// d = 32*(cl>>2) + 4*t + (cl&3), k = ks*32 + qg*8 + j.
// After MFMA, lane (qg,cl) owns C rows qg*4+i = dims 32qg+4t+i.
__global__ __launch_bounds__(1024) void prepack_kernel(
    const float* __restrict__ sw1, short8v* __restrict__ WtG) {
  int tid = threadIdx.x;
  int t = tid >> 7, ks = (tid >> 6) & 1, lane = tid & 63;
  int qg = lane >> 4, cl = lane & 15;
  int d = 32 * (cl >> 2) + 4 * t + (cl & 3);
  short8v fr;
#pragma unroll
  for (int j = 0; j < 8; ++j)
    fr[j] = f2bs(sw1[(128 + ks * 32 + qg * 8 + j) * 128 + d]);
  WtG[tid] = fr;
}

// Node projections -> interleaved bf16 rows [N][256]:
// SRCP[n] = [GA(32qg..)|SA(32qg..)] x4 qg-chunks; DSTP[n] = [GB|SB] same.
__global__ __launch_bounds__(256) void nodeproj_kernel(
    const float* __restrict__ h, const float* __restrict__ gw1,
    const float* __restrict__ sw1, __hip_bfloat16* __restrict__ SRCP,
    __hip_bfloat16* __restrict__ DSTP) {
  __shared__ float hs[64][64];   // [k][n]
  __shared__ float Ws[64][128];  // [k][c]
  int part = blockIdx.y;
  const float* W = (part & 1) ? sw1 : gw1;
  int roff = (part >= 2) ? 64 : 0;
  __hip_bfloat16* outp = (part >= 2) ? DSTP : SRCP;
  int goff = (part & 1) ? 32 : 0;
  int n0 = blockIdx.x * 64;
  int t = threadIdx.x;

  {
    int n = t & 63, kc = t >> 6;
    int gn = n0 + n;
#pragma unroll
    for (int i = 0; i < 4; ++i) {
      int k = kc * 16 + i * 4;
      float4 hv = make_float4(0.f, 0.f, 0.f, 0.f);
      if (gn < NN) hv = *(const float4*)&h[gn * 64 + k];
      hs[k + 0][n] = hv.x; hs[k + 1][n] = hv.y;
      hs[k + 2][n] = hv.z; hs[k + 3][n] = hv.w;
    }
  }
  {
    const float* Wb = W + roff * 128;
    float* wsf = &Ws[0][0];
#pragma unroll
    for (int i = 0; i < 8; ++i) {
      int flat = (i * 256 + t) * 4;
      *(float4*)&wsf[flat] = *(const float4*)&Wb[flat];
    }
  }
  __syncthreads();

  int tx = t & 31, ty = t >> 5;
  float acc[8][4] = {};
#pragma unroll 4
  for (int k = 0; k < 64; ++k) {
    float hn[8];
    *(float4*)&hn[0] = *(const float4*)&hs[k][ty * 8];
    *(float4*)&hn[4] = *(const float4*)&hs[k][ty * 8 + 4];
    float wv[4];
#pragma unroll
    for (int i = 0; i < 4; ++i) wv[i] = Ws[k][tx + 32 * i];
#pragma unroll
    for (int j = 0; j < 8; ++j)
#pragma unroll
      for (int i = 0; i < 4; ++i) acc[j][i] += hn[j] * wv[i];
  }
#pragma unroll
  for (int j = 0; j < 8; ++j) {
    int gn = n0 + ty * 8 + j;
    if (gn < NN) {
#pragma unroll
      for (int i = 0; i < 4; ++i)
        outp[(size_t)gn * 256 + i * 64 + goff + tx] = __float2bfloat16(acc[j][i]);
    }
  }
}

// Fused edge kernel v4 (= v3 with compiler-chosen VGPR, no min-wave bound):
// per rt, each lane gathers ONE 128B contiguous block per src + per dst
// (8+8 x16B from 2 bases) + 4 e-loads. Score dims 32qg+4t+i.
__global__ __launch_bounds__(256) void edge_kernel(
    const float* __restrict__ e, const int* __restrict__ eidx,
    const int* __restrict__ ebat,
    const __hip_bfloat16* __restrict__ SRCP, const __hip_bfloat16* __restrict__ DSTP,
    const float* __restrict__ Qg, const short8v* __restrict__ WtG,
    const float* __restrict__ sb1, const float* __restrict__ gw2,
    const float* __restrict__ gb2, const float* __restrict__ sw2,
    const float* __restrict__ sb2, float* __restrict__ out,
    float* __restrict__ nsum) {
  __shared__ short8v WtS[1024];    // 16 KB W fragments
  __shared__ f32x4 QgS[16 * 33];   // 8.4 KB padded
  __shared__ f32x4 gw2S[32], sb1S[32], sw2S[32];  // 1.5 KB
  const int tid = threadIdx.x;
  const int w = tid >> 6, lane = tid & 63;
  const int qg = lane >> 4, cl = lane & 15;
  const int EB = blockIdx.x * 256 + w * 64;
  const unsigned short* SU = (const unsigned short*)SRCP;
  const unsigned short* DU = (const unsigned short*)DSTP;
  const float sb2v = sb2[0], gb2v = gb2[0];

  // prefetch rt=0 indices (overlaps LDS staging)
  int srcv = eidx[EB + cl];
  int dstv = eidx[NE + EB + cl];
  int gv   = ebat[EB + cl];

  {  // stage LDS
    const f32x4* s4 = (const f32x4*)WtG;
    f32x4* d4 = (f32x4*)WtS;
#pragma unroll
    for (int i = 0; i < 4; ++i) d4[tid + i * 256] = s4[tid + i * 256];
    const f32x4* q4 = (const f32x4*)Qg;
    QgS[(tid >> 5) * 33 + (tid & 31)] = q4[tid];
    {
      int t2 = tid + 256;
      QgS[(t2 >> 5) * 33 + (t2 & 31)] = q4[t2];
    }
    if (tid < 32) {
      gw2S[tid] = ((const f32x4*)gw2)[tid];
      sb1S[tid] = ((const f32x4*)sb1)[tid];
      sw2S[tid] = ((const f32x4*)sw2)[tid];
    }
  }
  __syncthreads();

#pragma unroll 1
  for (int rt = 0; rt < 4; ++rt) {
    const int erow = EB + rt * 16 + cl;  // this lane's edge

    // ---- issue ALL loads for this rt upfront ----
    const float* ap = e + (size_t)erow * 64 + qg * 8;
    f32x4 f0 = __builtin_nontemporal_load((const f32x4*)(ap + 0));
    f32x4 f1 = __builtin_nontemporal_load((const f32x4*)(ap + 4));
    f32x4 f2 = __builtin_nontemporal_load((const f32x4*)(ap + 32));
    f32x4 f3 = __builtin_nontemporal_load((const f32x4*)(ap + 36));

    // src row: 128B contiguous = [gate 64B | score 64B] for this qg
    const ushort8v* sp = (const ushort8v*)(SU + (size_t)srcv * 256 + qg * 64);
    const ushort8v* dp = (const ushort8v*)(DU + (size_t)dstv * 256 + qg * 64);
    ushort8v gav[4], gbv[4], sav[4], sbv[4];
#pragma unroll
    for (int c = 0; c < 4; ++c) {
      gav[c] = sp[c];
      gbv[c] = dp[c];
      sav[c] = sp[4 + c];
      sbv[c] = dp[4 + c];
    }

    // prefetch next rt's indices (named scalars)
    int srcn = srcv, dstn = dstv, gn = gv;
    if (rt < 3) {
      int er2 = erow + 16;
      srcn = eidx[er2];
      dstn = eidx[NE + er2];
      gn   = ebat[er2];
    }

    // e -> bf16 fragments while gathers are in flight
    short8v b0, b1;
    b0[0] = f2bs(f0.x); b0[1] = f2bs(f0.y); b0[2] = f2bs(f0.z); b0[3] = f2bs(f0.w);
    b0[4] = f2bs(f1.x); b0[5] = f2bs(f1.y); b0[6] = f2bs(f1.z); b0[7] = f2bs(f1.w);
    b1[0] = f2bs(f2.x); b1[1] = f2bs(f2.y); b1[2] = f2bs(f2.z); b1[3] = f2bs(f2.w);
    b1[4] = f2bs(f3.x); b1[5] = f2bs(f3.y); b1[6] = f2bs(f3.z); b1[7] = f2bs(f3.w);

    // ---- gate compute: dims 32qg+8c+k ----
    float gpart = 0.f;
#pragma unroll
    for (int c = 0; c < 4; ++c) {
      ushort8v av = gav[c], bv = gbv[c];
      f32x4 q0 = QgS[gv * 33 + qg * 8 + c * 2];
      f32x4 q1 = QgS[gv * 33 + qg * 8 + c * 2 + 1];
      f32x4 w0 = gw2S[qg * 8 + c * 2];
      f32x4 w1 = gw2S[qg * 8 + c * 2 + 1];
#pragma unroll
      for (int ii = 0; ii < 4; ++ii) {
        float x = b2f(av[ii]) + b2f(bv[ii]) + q0[ii];
        gpart = fmaf(fmaxf(x, 0.f), w0[ii], gpart);
      }
#pragma unroll
      for (int ii = 0; ii < 4; ++ii) {
        float x = b2f(av[4 + ii]) + b2f(bv[4 + ii]) + q1[ii];
        gpart = fmaf(fmaxf(x, 0.f), w1[ii], gpart);
      }
    }

    // ---- score compute: MFMA + epilogue (lane dims 32qg+4t+i) ----
    float part = 0.f;
#pragma unroll
    for (int t = 0; t < 8; ++t) {
      short8v Aw0 = WtS[(t * 2 + 0) * 64 + lane];
      short8v Aw1 = WtS[(t * 2 + 1) * 64 + lane];
      f32x4 acc = (f32x4){0.f, 0.f, 0.f, 0.f};
      acc = __builtin_amdgcn_mfma_f32_16x16x32_bf16(Aw0, b0, acc, 0, 0, 0);
      acc = __builtin_amdgcn_mfma_f32_16x16x32_bf16(Aw1, b1, acc, 0, 0, 0);
      f32x4 bb = sb1S[qg * 8 + t];
      f32x4 ww = sw2S[qg * 8 + t];
#pragma unroll
      for (int i = 0; i < 4; ++i) {
        float sx = acc[i] + b2f(sav[t >> 1][(t & 1) * 4 + i]) +
                   b2f(sbv[t >> 1][(t & 1) * 4 + i]) + bb[i];
        part = fmaf(fmaxf(sx, 0.f), ww[i], part);
      }
    }

    // ---- reduce over qg groups; finalize ----
    part += __shfl_xor(part, 16, 64);
    part += __shfl_xor(part, 32, 64);
    gpart += __shfl_xor(gpart, 16, 64);
    gpart += __shfl_xor(gpart, 32, 64);
    if (lane < 16) {
      int E = EB + rt * 16 + cl;
      float gate = 1.f / (1.f + __expf(-(gpart + gb2v)));
      float ex = __expf(gate * (part + sb2v));
      out[E] = ex;
      atomicAdd(&nsum[dstv], ex);
    }
    srcv = srcn; dstv = dstn; gv = gn;
  }
}

__global__ __launch_bounds__(256) void norm_kernel(
    const int* __restrict__ eidx, const float* __restrict__ nodesum,
    float* __restrict__ out) {
  int ee = blockIdx.x * 256 + threadIdx.x;
  int dst = eidx[NE + ee];
  out[ee] = out[ee] / fmaxf(nodesum[dst], 1e-9f);
}

extern "C" void kernel_launch(void* const* d_in, const int* in_sizes, int n_in,
                              void* d_out, int out_size, void* d_ws, size_t ws_size,
                              hipStream_t stream) {
  const float* h   = (const float*)d_in[0];
  const float* e   = (const float*)d_in[1];
  const float* q   = (const float*)d_in[2];
  const int* eidx  = (const int*)d_in[3];
  const int* ebat  = (const int*)d_in[4];
  const float* gw1 = (const float*)d_in[5];
  const float* gb1 = (const float*)d_in[6];
  const float* gw2 = (const float*)d_in[7];
  const float* gb2 = (const float*)d_in[8];
  const float* sw1 = (const float*)d_in[9];
  const float* sb1 = (const float*)d_in[10];
  const float* sw2 = (const float*)d_in[11];
  const float* sb2 = (const float*)d_in[12];
  float* out = (float*)d_out;

  char* ws = (char*)d_ws;
  // SRCP 51.2MB | DSTP 51.2MB | Qg 8KB | WtG 16KB | nsum 400KB
  __hip_bfloat16* SRCP = (__hip_bfloat16*)ws;
  __hip_bfloat16* DSTP = (__hip_bfloat16*)(ws + 51200000);
  float* Qg    = (float*)(ws + 102400000);
  short8v* WtG = (short8v*)(ws + 102400000 + 8192);
  float* nsum  = (float*)(ws + 102400000 + 8192 + 16384);

  (void)hipMemsetAsync(nsum, 0, 400000, stream);
  qproj_kernel<<<dim3(16), dim3(128), 0, stream>>>(q, gw1, gb1, Qg);
  prepack_kernel<<<dim3(1), dim3(1024), 0, stream>>>(sw1, WtG);
  nodeproj_kernel<<<dim3(1563, 4), dim3(256), 0, stream>>>(h, gw1, sw1, SRCP, DSTP);
  edge_kernel<<<dim3(NE / 256), dim3(256), 0, stream>>>(
      e, eidx, ebat, SRCP, DSTP, Qg, WtG, sb1, gw2, gb2, sw2, sb2, out, nsum);
  norm_kernel<<<dim3(NE / 256), dim3(256), 0, stream>>>(eidx, nsum, out);
}

// Round 11
// 529.537 us; speedup vs baseline: 2.2306x; 1.0338x over previous
//
#include <hip/hip_runtime.h>
#include <hip/hip_bf16.h>

#define NN 100000
#define NE 1600000
// D_H = D_E = D_Q = 64, D_HID = 128, N_GRAPHS = 16

typedef __attribute__((ext_vector_type(8))) unsigned short ushort8v;
typedef __attribute__((ext_vector_type(8))) short short8v;
typedef __attribute__((ext_vector_type(4))) float f32x4;

__device__ __forceinline__ float b2f(unsigned short u) {
  return __uint_as_float(((unsigned)u) << 16);
}
// f32 -> bf16 bits, round-to-nearest-even
__device__ __forceinline__ short f2bs(float f) {
  unsigned u = __float_as_uint(f);
  unsigned r = (u + 0x7FFFu + ((u >> 16) & 1u)) >> 16;
  return (short)r;
}

// Qg[g][j] = gate_b1[j] + sum_k q[g][k] * gate_w1[128+k][j]
__global__ void qproj_kernel(const float* __restrict__ q,
                             const float* __restrict__ gw1,
                             const float* __restrict__ gb1,
                             float* __restrict__ Qg) {
  int g = blockIdx.x, j = threadIdx.x;
  float acc = gb1[j];
  for (int k = 0; k < 64; ++k) acc += q[g * 64 + k] * gw1[(128 + k) * 128 + j];
  Qg[g * 128 + j] = acc;
}

// Prepack score_w1 e-part into bf16 MFMA A-fragments with REMAPPED rows:
// tile (t,ks), lane (qg,cl), elem j -> A row cl = hidden dim
// d = 32*(cl>>2) + 4*t + (cl&3), k = ks*32 + qg*8 + j.
// After MFMA, lane (qg,cl) owns C rows qg*4+i = dims 32qg+4t+i.
__global__ __launch_bounds__(1024) void prepack_kernel(
    const float* __restrict__ sw1, short8v* __restrict__ WtG) {
  int tid = threadIdx.x;
  int t = tid >> 7, ks = (tid >> 6) & 1, lane = tid & 63;
  int qg = lane >> 4, cl = lane & 15;
  int d = 32 * (cl >> 2) + 4 * t + (cl & 3);
  short8v fr;
#pragma unroll
  for (int j = 0; j < 8; ++j)
    fr[j] = f2bs(sw1[(128 + ks * 32 + qg * 8 + j) * 128 + d]);
  WtG[tid] = fr;
}

// Node projections -> interleaved bf16 rows [N][256]:
// SRCP[n] = [GA(32qg..)|SA(32qg..)] x4 qg-chunks; DSTP[n] = [GB|SB] same.
__global__ __launch_bounds__(256) void nodeproj_kernel(
    const float* __restrict__ h, const float* __restrict__ gw1,
    const float* __restrict__ sw1, __hip_bfloat16* __restrict__ SRCP,
    __hip_bfloat16* __restrict__ DSTP) {
  __shared__ float hs[64][64];   // [k][n]
  __shared__ float Ws[64][128];  // [k][c]
  int part = blockIdx.y;
  const float* W = (part & 1) ? sw1 : gw1;
  int roff = (part >= 2) ? 64 : 0;
  __hip_bfloat16* outp = (part >= 2) ? DSTP : SRCP;
  int goff = (part & 1) ? 32 : 0;
  int n0 = blockIdx.x * 64;
  int t = threadIdx.x;

  {
    int n = t & 63, kc = t >> 6;
    int gn = n0 + n;
#pragma unroll
    for (int i = 0; i < 4; ++i) {
      int k = kc * 16 + i * 4;
      float4 hv = make_float4(0.f, 0.f, 0.f, 0.f);
      if (gn < NN) hv = *(const float4*)&h[gn * 64 + k];
      hs[k + 0][n] = hv.x; hs[k + 1][n] = hv.y;
      hs[k + 2][n] = hv.z; hs[k + 3][n] = hv.w;
    }
  }
  {
    const float* Wb = W + roff * 128;
    float* wsf = &Ws[0][0];
#pragma unroll
    for (int i = 0; i < 8; ++i) {
      int flat = (i * 256 + t) * 4;
      *(float4*)&wsf[flat] = *(const float4*)&Wb[flat];
    }
  }
  __syncthreads();

  int tx = t & 31, ty = t >> 5;
  float acc[8][4] = {};
#pragma unroll 4
  for (int k = 0; k < 64; ++k) {
    float hn[8];
    *(float4*)&hn[0] = *(const float4*)&hs[k][ty * 8];
    *(float4*)&hn[4] = *(const float4*)&hs[k][ty * 8 + 4];
    float wv[4];
#pragma unroll
    for (int i = 0; i < 4; ++i) wv[i] = Ws[k][tx + 32 * i];
#pragma unroll
    for (int j = 0; j < 8; ++j)
#pragma unroll
      for (int i = 0; i < 4; ++i) acc[j][i] += hn[j] * wv[i];
  }
#pragma unroll
  for (int j = 0; j < 8; ++j) {
    int gn = n0 + ty * 8 + j;
    if (gn < NN) {
#pragma unroll
      for (int i = 0; i < 4; ++i)
        outp[(size_t)gn * 256 + i * 64 + goff + tx] = __float2bfloat16(acc[j][i]);
    }
  }
}

// Fused edge kernel v5: depth-1 software pipeline over rt with two named
// register buffers. Every compute overlaps the next rt's 20 loads.
// Lane (qg,cl): edge cl per rt; gate dims 32qg+8c+k; score dims 32qg+4t+i.
__global__ __launch_bounds__(256, 2) void edge_kernel(
    const float* __restrict__ e, const int* __restrict__ eidx,
    const int* __restrict__ ebat,
    const __hip_bfloat16* __restrict__ SRCP, const __hip_bfloat16* __restrict__ DSTP,
    const float* __restrict__ Qg, const short8v* __restrict__ WtG,
    const float* __restrict__ sb1, const float* __restrict__ gw2,
    const float* __restrict__ gb2, const float* __restrict__ sw2,
    const float* __restrict__ sb2, float* __restrict__ out,
    float* __restrict__ nsum) {
  __shared__ short8v WtS[1024];    // 16 KB W fragments
  __shared__ f32x4 QgS[16 * 33];   // 8.4 KB padded
  __shared__ f32x4 gw2S[32], sb1S[32], sw2S[32];  // 1.5 KB
  const int tid = threadIdx.x;
  const int w = tid >> 6, lane = tid & 63;
  const int qg = lane >> 4, cl = lane & 15;
  const int EB = blockIdx.x * 256 + w * 64;
  const unsigned short* SU = (const unsigned short*)SRCP;
  const unsigned short* DU = (const unsigned short*)DSTP;
  const float sb2v = sb2[0], gb2v = gb2[0];

  // all 4 rts' indices upfront (independent loads, overlap LDS staging)
  const int src0 = eidx[EB + cl],      src1 = eidx[EB + 16 + cl];
  const int src2 = eidx[EB + 32 + cl], src3 = eidx[EB + 48 + cl];
  const int dst0 = eidx[NE + EB + cl],      dst1 = eidx[NE + EB + 16 + cl];
  const int dst2 = eidx[NE + EB + 32 + cl], dst3 = eidx[NE + EB + 48 + cl];
  const int g0 = ebat[EB + cl],      g1 = ebat[EB + 16 + cl];
  const int g2 = ebat[EB + 32 + cl], g3 = ebat[EB + 48 + cl];

  {  // stage LDS
    const f32x4* s4 = (const f32x4*)WtG;
    f32x4* d4 = (f32x4*)WtS;
#pragma unroll
    for (int i = 0; i < 4; ++i) d4[tid + i * 256] = s4[tid + i * 256];
    const f32x4* q4 = (const f32x4*)Qg;
    QgS[(tid >> 5) * 33 + (tid & 31)] = q4[tid];
    {
      int t2 = tid + 256;
      QgS[(t2 >> 5) * 33 + (t2 & 31)] = q4[t2];
    }
    if (tid < 32) {
      gw2S[tid] = ((const f32x4*)gw2)[tid];
      sb1S[tid] = ((const f32x4*)sb1)[tid];
      sw2S[tid] = ((const f32x4*)sw2)[tid];
    }
  }
  __syncthreads();

  struct Buf {
    f32x4 f[4];      // e row slice (f32)
    ushort8v s[8];   // src 128B block: [gate 64B | score 64B]
    ushort8v d[8];   // dst 128B block
  };
  Buf A, B;

  auto stage = [&](Buf& S, int erow0, int srcv, int dstv) {
    const float* ap = e + (size_t)(erow0 + cl) * 64 + qg * 8;
    S.f[0] = __builtin_nontemporal_load((const f32x4*)(ap + 0));
    S.f[1] = __builtin_nontemporal_load((const f32x4*)(ap + 4));
    S.f[2] = __builtin_nontemporal_load((const f32x4*)(ap + 32));
    S.f[3] = __builtin_nontemporal_load((const f32x4*)(ap + 36));
    const ushort8v* sp = (const ushort8v*)(SU + (size_t)srcv * 256 + qg * 64);
    const ushort8v* dp = (const ushort8v*)(DU + (size_t)dstv * 256 + qg * 64);
#pragma unroll
    for (int c = 0; c < 8; ++c) {
      S.s[c] = sp[c];
      S.d[c] = dp[c];
    }
  };

  auto compute = [&](Buf& S, int erow0, int dstv, int gv) {
    // e -> bf16 fragments
    short8v b0, b1;
    b0[0] = f2bs(S.f[0].x); b0[1] = f2bs(S.f[0].y); b0[2] = f2bs(S.f[0].z); b0[3] = f2bs(S.f[0].w);
    b0[4] = f2bs(S.f[1].x); b0[5] = f2bs(S.f[1].y); b0[6] = f2bs(S.f[1].z); b0[7] = f2bs(S.f[1].w);
    b1[0] = f2bs(S.f[2].x); b1[1] = f2bs(S.f[2].y); b1[2] = f2bs(S.f[2].z); b1[3] = f2bs(S.f[2].w);
    b1[4] = f2bs(S.f[3].x); b1[5] = f2bs(S.f[3].y); b1[6] = f2bs(S.f[3].z); b1[7] = f2bs(S.f[3].w);

    // gate: dims 32qg+8c+k
    float gpart = 0.f;
#pragma unroll
    for (int c = 0; c < 4; ++c) {
      ushort8v av = S.s[c], bv = S.d[c];
      f32x4 q0 = QgS[gv * 33 + qg * 8 + c * 2];
      f32x4 q1 = QgS[gv * 33 + qg * 8 + c * 2 + 1];
      f32x4 w0 = gw2S[qg * 8 + c * 2];
      f32x4 w1 = gw2S[qg * 8 + c * 2 + 1];
#pragma unroll
      for (int ii = 0; ii < 4; ++ii) {
        float x = b2f(av[ii]) + b2f(bv[ii]) + q0[ii];
        gpart = fmaf(fmaxf(x, 0.f), w0[ii], gpart);
      }
#pragma unroll
      for (int ii = 0; ii < 4; ++ii) {
        float x = b2f(av[4 + ii]) + b2f(bv[4 + ii]) + q1[ii];
        gpart = fmaf(fmaxf(x, 0.f), w1[ii], gpart);
      }
    }

    // score: MFMA + epilogue (lane dims 32qg+4t+i)
    float part = 0.f;
#pragma unroll
    for (int t = 0; t < 8; ++t) {
      short8v Aw0 = WtS[(t * 2 + 0) * 64 + lane];
      short8v Aw1 = WtS[(t * 2 + 1) * 64 + lane];
      f32x4 acc = (f32x4){0.f, 0.f, 0.f, 0.f};
      acc = __builtin_amdgcn_mfma_f32_16x16x32_bf16(Aw0, b0, acc, 0, 0, 0);
      acc = __builtin_amdgcn_mfma_f32_16x16x32_bf16(Aw1, b1, acc, 0, 0, 0);
      f32x4 bb = sb1S[qg * 8 + t];
      f32x4 ww = sw2S[qg * 8 + t];
#pragma unroll
      for (int i = 0; i < 4; ++i) {
        float sx = acc[i] + b2f(S.s[4 + (t >> 1)][(t & 1) * 4 + i]) +
                   b2f(S.d[4 + (t >> 1)][(t & 1) * 4 + i]) + bb[i];
        part = fmaf(fmaxf(sx, 0.f), ww[i], part);
      }
    }

    part += __shfl_xor(part, 16, 64);
    part += __shfl_xor(part, 32, 64);
    gpart += __shfl_xor(gpart, 16, 64);
    gpart += __shfl_xor(gpart, 32, 64);
    if (lane < 16) {
      int E = erow0 + cl;
      float gate = 1.f / (1.f + __expf(-(gpart + gb2v)));
      float ex = __expf(gate * (part + sb2v));
      out[E] = ex;
      atomicAdd(&nsum[dstv], ex);
    }
  };

  // depth-1 pipeline: every compute has the next rt's loads in flight
  stage(A, EB, src0, dst0);
  stage(B, EB + 16, src1, dst1);
  compute(A, EB, dst0, g0);
  stage(A, EB + 32, src2, dst2);
  compute(B, EB + 16, dst1, g1);
  stage(B, EB + 48, src3, dst3);
  compute(A, EB + 32, dst2, g2);
  compute(B, EB + 48, dst3, g3);
}

__global__ __launch_bounds__(256) void norm_kernel(
    const int* __restrict__ eidx, const float* __restrict__ nodesum,
    float* __restrict__ out) {
  int ee = blockIdx.x * 256 + threadIdx.x;
  int dst = eidx[NE + ee];
  out[ee] = out[ee] / fmaxf(nodesum[dst], 1e-9f);
}

extern "C" void kernel_launch(void* const* d_in, const int* in_sizes, int n_in,
                              void* d_out, int out_size, void* d_ws, size_t ws_size,
                              hipStream_t stream) {
  const float* h   = (const float*)d_in[0];
  const float* e   = (const float*)d_in[1];
  const float* q   = (const float*)d_in[2];
  const int* eidx  = (const int*)d_in[3];
  const int* ebat  = (const int*)d_in[4];
  const float* gw1 = (const float*)d_in[5];
  const float* gb1 = (const float*)d_in[6];
  const float* gw2 = (const float*)d_in[7];
  const float* gb2 = (const float*)d_in[8];
  const float* sw1 = (const float*)d_in[9];
  const float* sb1 = (const float*)d_in[10];
  const float* sw2 = (const float*)d_in[11];
  const float* sb2 = (const float*)d_in[12];
  float* out = (float*)d_out;

  char* ws = (char*)d_ws;
  // SRCP 51.2MB | DSTP 51.2MB | Qg 8KB | WtG 16KB | nsum 400KB
  __hip_bfloat16* SRCP = (__hip_bfloat16*)ws;
  __hip_bfloat16* DSTP = (__hip_bfloat16*)(ws + 51200000);
  float* Qg    = (float*)(ws + 102400000);
  short8v* WtG = (short8v*)(ws + 102400000 + 8192);
  float* nsum  = (float*)(ws + 102400000 + 8192 + 16384);

  (void)hipMemsetAsync(nsum, 0, 400000, stream);
  qproj_kernel<<<dim3(16), dim3(128), 0, stream>>>(q, gw1, gb1, Qg);
  prepack_kernel<<<dim3(1), dim3(1024), 0, stream>>>(sw1, WtG);
  nodeproj_kernel<<<dim3(1563, 4), dim3(256), 0, stream>>>(h, gw1, sw1, SRCP, DSTP);
  edge_kernel<<<dim3(NE / 256), dim3(256), 0, stream>>>(
      e, eidx, ebat, SRCP, DSTP, Qg, WtG, sb1, gw2, gb2, sw2, sb2, out, nsum);
  norm_kernel<<<dim3(NE / 256), dim3(256), 0, stream>>>(eidx, nsum, out);
}